// Round 1
// baseline (185.117 us; speedup 1.0000x reference)
//
#include <hip/hip_runtime.h>

#define L_LEN   262144
#define OUT_LEN 262142
#define BATCH   32

struct KPtrs { const float* p[12]; };

// ---------------- Kernel 1a: pooled[256] = mean over 1024-elem bins of x[0] ----------------
__global__ void pool_kernel(const float* __restrict__ x, float* __restrict__ pooled) {
    int bin = blockIdx.x;          // 256 blocks
    int tid = threadIdx.x;         // 256 threads
    const float4* x4 = (const float4*)(x + bin * 1024);
    float4 v = x4[tid];
    float sum = v.x + v.y + v.z + v.w;
    #pragma unroll
    for (int off = 32; off; off >>= 1) sum += __shfl_down(sum, off);
    __shared__ float wred[4];
    int wave = tid >> 6;
    if ((tid & 63) == 0) wred[wave] = sum;
    __syncthreads();
    if (tid == 0)
        pooled[bin] = (wred[0] + wred[1] + wred[2] + wred[3]) * (1.0f / 1024.0f);
}

// ---------------- Kernel 1b: attention MLP -> softmax s[12] -> raw effective kernels ----------------
// Kraw layout: [5 classes][4 ch][11 taps]; class q includes kernels with k <= 2q+3.
__global__ void attn_kernel(const float* __restrict__ w1, const float* __restrict__ b1,
                            const float* __restrict__ w2, const float* __restrict__ b2,
                            KPtrs kp, const float* __restrict__ pooled_g,
                            float* __restrict__ s_out, float* __restrict__ Kraw,
                            double* __restrict__ acc) {
    __shared__ float pooled[256];
    __shared__ float h[128];
    __shared__ float logits[12];
    __shared__ float s[12];
    int tid = threadIdx.x;
    pooled[tid] = pooled_g[tid];
    __syncthreads();
    if (tid < 128) {
        float a = b1[tid];
        const float* wr = w1 + tid * 256;
        #pragma unroll 4
        for (int d = 0; d < 256; ++d) a = fmaf(pooled[d], wr[d], a);
        h[tid] = fmaxf(a, 0.0f);
    }
    __syncthreads();
    if (tid < 12) {
        float a = b2[tid];
        const float* wr = w2 + tid * 128;
        #pragma unroll 4
        for (int j = 0; j < 128; ++j) a = fmaf(h[j], wr[j], a);
        logits[tid] = a;
    }
    __syncthreads();
    if (tid == 0) {
        float m = logits[0];
        #pragma unroll
        for (int i = 1; i < 12; ++i) m = fmaxf(m, logits[i]);
        float e[12]; float sum = 0.0f;
        #pragma unroll
        for (int i = 0; i < 12; ++i) { e[i] = expf(logits[i] - m); sum += e[i]; }
        float inv = 1.0f / sum;
        #pragma unroll
        for (int i = 0; i < 12; ++i) s[i] = e[i] * inv;
    }
    __syncthreads();
    if (tid < 12) s_out[tid] = s[tid];
    if (tid < 8)  acc[tid] = 0.0;   // zero stats accumulators (ws is poisoned, not re-zeroed)
    constexpr int KSa[12] = {3,3,3,5,5,7,7,7,9,9,11,11};
    if (tid < 220) {
        int q = tid / 44, r = tid % 44, c = r / 11, j = r % 11;
        int kmax = 2 * q + 3;
        float v = 0.0f;
        #pragma unroll
        for (int i = 0; i < 12; ++i) {
            int k = KSa[i];
            if (k <= kmax && j < k) v = fmaf(s[i], kp.p[i][c * k + j], v);
        }
        Kraw[tid] = v;
    }
}

// ---------------- Kernel 2: stats pass — conv (recompute) -> per-channel sum & sumsq ----------------
__global__ __launch_bounds__(256) void stats_kernel(const float* __restrict__ x,
                                                    const float* __restrict__ Kraw,
                                                    double* __restrict__ acc) {
    float Kc[4][11];
    const float* K4 = Kraw + 4 * 44;    // full class (kmax=11)
    #pragma unroll
    for (int c = 0; c < 4; ++c)
        #pragma unroll
        for (int j = 0; j < 11; ++j) Kc[c][j] = K4[c * 11 + j];

    float ssum[4] = {0,0,0,0}, ssq[4] = {0,0,0,0};
    int nth = gridDim.x * blockDim.x;
    for (int cid = blockIdx.x * blockDim.x + threadIdx.x; cid < BATCH * 65536; cid += nth) {
        int b  = cid >> 16;
        int ch = cid & 65535;
        int t0 = ch << 2;
        const float* xb = x + b * L_LEN;
        if (ch <= 65532) {
            const float4* xp = (const float4*)(xb + t0);
            float4 a0 = xp[0], a1 = xp[1], a2 = xp[2], a3 = xp[3];
            float xv[16];
            xv[0]=a0.x; xv[1]=a0.y; xv[2]=a0.z; xv[3]=a0.w;
            xv[4]=a1.x; xv[5]=a1.y; xv[6]=a1.z; xv[7]=a1.w;
            xv[8]=a2.x; xv[9]=a2.y; xv[10]=a2.z; xv[11]=a2.w;
            xv[12]=a3.x; xv[13]=a3.y; xv[14]=a3.z; xv[15]=a3.w;
            #pragma unroll
            for (int c = 0; c < 4; ++c) {
                float v0 = 0.f, v1 = 0.f, v2 = 0.f, v3 = 0.f;
                #pragma unroll
                for (int j = 0; j < 11; ++j) {
                    float k = Kc[c][j];
                    v0 = fmaf(k, xv[j],     v0);
                    v1 = fmaf(k, xv[j + 1], v1);
                    v2 = fmaf(k, xv[j + 2], v2);
                    v3 = fmaf(k, xv[j + 3], v3);
                }
                ssum[c] += (v0 + v1) + (v2 + v3);
                ssq[c] = fmaf(v0, v0, ssq[c]);
                ssq[c] = fmaf(v1, v1, ssq[c]);
                ssq[c] = fmaf(v2, v2, ssq[c]);
                ssq[c] = fmaf(v3, v3, ssq[c]);
            }
        } else {
            // tail: per-position cumulative kernel class
            for (int tt = 0; tt < 4; ++tt) {
                int t = t0 + tt;
                if (t >= OUT_LEN) break;
                int rem = L_LEN - t;                 // 3..12 here
                int q = (rem - 3) >> 1; if (q > 4) q = 4;
                int kmax = 2 * q + 3;
                const float* Kq = Kraw + q * 44;
                for (int c = 0; c < 4; ++c) {
                    float a = 0.0f;
                    for (int j = 0; j < kmax; ++j) a = fmaf(Kq[c * 11 + j], xb[t + j], a);
                    ssum[c] += a;
                    ssq[c] = fmaf(a, a, ssq[c]);
                }
            }
        }
    }
    // block reduce 8 partials, then one double atomic per value
    #pragma unroll
    for (int c = 0; c < 4; ++c) {
        #pragma unroll
        for (int off = 32; off; off >>= 1) {
            ssum[c] += __shfl_down(ssum[c], off);
            ssq[c]  += __shfl_down(ssq[c],  off);
        }
    }
    __shared__ float red[4][8];
    int wave = threadIdx.x >> 6;
    if ((threadIdx.x & 63) == 0) {
        #pragma unroll
        for (int c = 0; c < 4; ++c) { red[wave][c] = ssum[c]; red[wave][4 + c] = ssq[c]; }
    }
    __syncthreads();
    if (threadIdx.x < 8) {
        float v = red[0][threadIdx.x] + red[1][threadIdx.x] + red[2][threadIdx.x] + red[3][threadIdx.x];
        atomicAdd(&acc[threadIdx.x], (double)v);
    }
}

// ---------------- Kernel 2b: fold BN into kernel taps + bias ----------------
__global__ void finalize_kernel(const double* __restrict__ acc,
                                const float* __restrict__ gamma, const float* __restrict__ beta,
                                const float* __restrict__ Kraw,
                                float* __restrict__ Kscl, float* __restrict__ biasOut) {
    __shared__ float g[4];
    int tid = threadIdx.x;
    if (tid < 4) {
        double N = (double)BATCH * (double)OUT_LEN;
        double mean = acc[tid] / N;
        double var  = acc[4 + tid] / N - mean * mean;
        float gg = gamma[tid] * (float)(1.0 / sqrt(var + 1e-5));
        g[tid] = gg;
        biasOut[tid] = beta[tid] - (float)mean * gg;
    }
    __syncthreads();
    if (tid < 220) {
        int c = (tid / 11) % 4;
        Kscl[tid] = Kraw[tid] * g[c];
    }
}

// ---------------- Kernel 3: write pass — conv with BN-folded taps, ReLU, store ----------------
__global__ __launch_bounds__(256) void write_kernel(const float* __restrict__ x,
                                                    const float* __restrict__ Kscl,
                                                    const float* __restrict__ biasv,
                                                    float* __restrict__ out) {
    float Kc[4][11];
    const float* K4 = Kscl + 4 * 44;
    #pragma unroll
    for (int c = 0; c < 4; ++c)
        #pragma unroll
        for (int j = 0; j < 11; ++j) Kc[c][j] = K4[c * 11 + j];
    float bias[4] = {biasv[0], biasv[1], biasv[2], biasv[3]};

    int nth = gridDim.x * blockDim.x;
    for (int cid = blockIdx.x * blockDim.x + threadIdx.x; cid < BATCH * 65536; cid += nth) {
        int b  = cid >> 16;
        int ch = cid & 65535;
        int t0 = ch << 2;
        const float* xb = x + b * L_LEN;
        if (ch <= 65532) {
            const float4* xp = (const float4*)(xb + t0);
            float4 a0 = xp[0], a1 = xp[1], a2 = xp[2], a3 = xp[3];
            float xv[16];
            xv[0]=a0.x; xv[1]=a0.y; xv[2]=a0.z; xv[3]=a0.w;
            xv[4]=a1.x; xv[5]=a1.y; xv[6]=a1.z; xv[7]=a1.w;
            xv[8]=a2.x; xv[9]=a2.y; xv[10]=a2.z; xv[11]=a2.w;
            xv[12]=a3.x; xv[13]=a3.y; xv[14]=a3.z; xv[15]=a3.w;
            #pragma unroll
            for (int c = 0; c < 4; ++c) {
                float v0 = bias[c], v1 = bias[c], v2 = bias[c], v3 = bias[c];
                #pragma unroll
                for (int j = 0; j < 11; ++j) {
                    float k = Kc[c][j];
                    v0 = fmaf(k, xv[j],     v0);
                    v1 = fmaf(k, xv[j + 1], v1);
                    v2 = fmaf(k, xv[j + 2], v2);
                    v3 = fmaf(k, xv[j + 3], v3);
                }
                v0 = fmaxf(v0, 0.f); v1 = fmaxf(v1, 0.f);
                v2 = fmaxf(v2, 0.f); v3 = fmaxf(v3, 0.f);
                // row base (b*4+c)*OUT_LEN is 8B-aligned (OUT_LEN even), t0 % 4 == 0
                float2* o2 = (float2*)(out + (b * 4 + c) * OUT_LEN + t0);
                o2[0] = make_float2(v0, v1);
                o2[1] = make_float2(v2, v3);
            }
        } else {
            for (int tt = 0; tt < 4; ++tt) {
                int t = t0 + tt;
                if (t >= OUT_LEN) break;
                int rem = L_LEN - t;
                int q = (rem - 3) >> 1; if (q > 4) q = 4;
                int kmax = 2 * q + 3;
                const float* Kq = Kscl + q * 44;
                for (int c = 0; c < 4; ++c) {
                    float a = bias[c];
                    for (int j = 0; j < kmax; ++j) a = fmaf(Kq[c * 11 + j], xb[t + j], a);
                    out[(b * 4 + c) * OUT_LEN + t] = fmaxf(a, 0.f);
                }
            }
        }
    }
}

extern "C" void kernel_launch(void* const* d_in, const int* in_sizes, int n_in,
                              void* d_out, int out_size, void* d_ws, size_t ws_size,
                              hipStream_t stream) {
    const float* x     = (const float*)d_in[0];
    const float* w1    = (const float*)d_in[1];
    const float* b1    = (const float*)d_in[2];
    const float* w2    = (const float*)d_in[3];
    const float* b2    = (const float*)d_in[4];
    const float* gamma = (const float*)d_in[5];
    const float* beta  = (const float*)d_in[6];
    KPtrs kp;
    for (int i = 0; i < 12; ++i) kp.p[i] = (const float*)d_in[7 + i];
    float* out = (float*)d_out;

    char* ws = (char*)d_ws;
    double* acc    = (double*)(ws + 0);      // 8 doubles: sum[4], sumsq[4]
    float*  pooled = (float*)(ws + 64);      // 256 floats
    float*  s_out  = (float*)(ws + 1088);    // 12 floats
    float*  Kraw   = (float*)(ws + 1152);    // 220 floats
    float*  Kscl   = (float*)(ws + 2048);    // 220 floats
    float*  biasv  = (float*)(ws + 2944);    // 4 floats

    pool_kernel<<<dim3(256), dim3(256), 0, stream>>>(x, pooled);
    attn_kernel<<<dim3(1), dim3(256), 0, stream>>>(w1, b1, w2, b2, kp, pooled, s_out, Kraw, acc);
    stats_kernel<<<dim3(2048), dim3(256), 0, stream>>>(x, Kraw, acc);
    finalize_kernel<<<dim3(1), dim3(256), 0, stream>>>(acc, gamma, beta, Kraw, Kscl, biasv);
    write_kernel<<<dim3(2048), dim3(256), 0, stream>>>(x, Kscl, biasv, out);
}